// Round 1
// baseline (439.188 us; speedup 1.0000x reference)
//
#include <hip/hip_runtime.h>

// LIF neuron scan: x [B,T,N] fp32 -> spikes [B,T,N] fp32
//   mem = 0.25*mem + x_t ; spike = mem > 1.0 ; mem = spike ? 0 : mem
// One thread per (b, n/4) chain, float4 vectorized, sequential over T.
// Memory-bound: 512 MiB total traffic, roofline ~85 us at 6.3 TB/s.

static constexpr int   T_STEPS = 128;
static constexpr int   N_FEAT  = 8192;
static constexpr float TAU     = 0.25f;
static constexpr float V_TH    = 1.0f;

__global__ __launch_bounds__(256) void lif_scan_kernel(
    const float4* __restrict__ x, float4* __restrict__ out, int n_chains) {
    const int N4  = N_FEAT / 4;                       // 2048 float4 per row
    int tid = blockIdx.x * blockDim.x + threadIdx.x;  // 0 .. B*N/4-1
    if (tid >= n_chains) return;

    int b  = tid / N4;
    int n4 = tid - b * N4;
    // float4 index of [b, t, n4] is (b*T + t)*N4 + n4
    size_t idx = (size_t)b * T_STEPS * N4 + n4;

    float4 mem = make_float4(0.f, 0.f, 0.f, 0.f);

#pragma unroll 4
    for (int t = 0; t < T_STEPS; ++t) {
        float4 xt = x[idx];
        float4 s;
        // 0.25*mem is exact (pow2 scale) -> bitwise matches mul+add reference
        mem.x = TAU * mem.x + xt.x;
        mem.y = TAU * mem.y + xt.y;
        mem.z = TAU * mem.z + xt.z;
        mem.w = TAU * mem.w + xt.w;
        s.x = (mem.x > V_TH) ? 1.f : 0.f;
        s.y = (mem.y > V_TH) ? 1.f : 0.f;
        s.z = (mem.z > V_TH) ? 1.f : 0.f;
        s.w = (mem.w > V_TH) ? 1.f : 0.f;
        mem.x = (mem.x > V_TH) ? 0.f : mem.x;
        mem.y = (mem.y > V_TH) ? 0.f : mem.y;
        mem.z = (mem.z > V_TH) ? 0.f : mem.z;
        mem.w = (mem.w > V_TH) ? 0.f : mem.w;
        out[idx] = s;
        idx += N4;
    }
}

extern "C" void kernel_launch(void* const* d_in, const int* in_sizes, int n_in,
                              void* d_out, int out_size, void* d_ws, size_t ws_size,
                              hipStream_t stream) {
    const float* x   = (const float*)d_in[0];
    float*       out = (float*)d_out;

    // total elems = B*T*N ; chains = B*N/4
    int total    = in_sizes[0];
    int n_chains = total / (T_STEPS * 4);
    int block    = 256;
    int grid     = (n_chains + block - 1) / block;

    lif_scan_kernel<<<grid, block, 0, stream>>>(
        (const float4*)x, (float4*)out, n_chains);
}

// Round 2
// 429.784 us; speedup vs baseline: 1.0219x; 1.0219x over previous
//
#include <hip/hip_runtime.h>

// LIF neuron scan: x [B,T,N] fp32 -> spikes [B,T,N] fp32
//   mem = 0.25*mem + x_t ; spike = mem > 1.0 ; mem = spike ? 0 : mem
//
// R1 change: scalar chain per thread (was float4). B*N = 524288 threads
// = 8192 waves = 32 waves/CU (max occupancy) vs 2048 waves (2/SIMD) before.
// The T-scan is a serial dependence chain; at 2 waves/SIMD the SIMDs idled
// on vmcnt waits (439 us = 1.2 TB/s). Wave-level parallelism is the robust
// latency-hider here; each wave access is still a coalesced 256 B txn.
// Nontemporal load/store: both streams touched exactly once (512 MiB total),
// skip cache allocation.

static constexpr int   T_STEPS = 128;
static constexpr int   N_FEAT  = 8192;
static constexpr float TAU     = 0.25f;
static constexpr float V_TH    = 1.0f;

__global__ __launch_bounds__(256) void lif_scan_kernel(
    const float* __restrict__ x, float* __restrict__ out, int n_chains) {
    int tid = blockIdx.x * blockDim.x + threadIdx.x;  // 0 .. B*N-1
    if (tid >= n_chains) return;

    int b = tid / N_FEAT;
    int n = tid - b * N_FEAT;
    // element index of [b, t, n] is (b*T + t)*N + n
    size_t idx = (size_t)b * T_STEPS * N_FEAT + n;

    float mem = 0.f;

#pragma unroll 4
    for (int t = 0; t < T_STEPS; ++t) {
        float xt = __builtin_nontemporal_load(&x[idx]);
        // 0.25*mem is exact (pow2 scale) -> bitwise matches numpy reference
        mem = TAU * mem + xt;
        float s = (mem > V_TH) ? 1.f : 0.f;
        mem     = (mem > V_TH) ? 0.f : mem;
        __builtin_nontemporal_store(s, &out[idx]);
        idx += N_FEAT;
    }
}

extern "C" void kernel_launch(void* const* d_in, const int* in_sizes, int n_in,
                              void* d_out, int out_size, void* d_ws, size_t ws_size,
                              hipStream_t stream) {
    const float* x   = (const float*)d_in[0];
    float*       out = (float*)d_out;

    int total    = in_sizes[0];          // B*T*N
    int n_chains = total / T_STEPS;      // B*N
    int block    = 256;
    int grid     = (n_chains + block - 1) / block;

    lif_scan_kernel<<<grid, block, 0, stream>>>(x, out, n_chains);
}

// Round 3
// 425.073 us; speedup vs baseline: 1.0332x; 1.0111x over previous
//
#include <hip/hip_runtime.h>

// LIF neuron scan: x [B,T,N] fp32 -> spikes [B,T,N] fp32
//   mem = 0.25*mem + x_t ; spike = mem > 1.0 ; mem = spike ? 0 : mem
//
// R2 change: explicit software-pipelined prefetch, depth 8. R0 (float4,
// 2 w/SIMD, unroll4) and R1 (scalar, 8 w/SIMD, unroll4) both achieved
// ~1.25 TB/s == identical 8 KiB/SIMD in flight, suggesting either (a) the
// compiler serialized the loop (1 load in flight/wave) or (b) bench dur_us
// is dominated by harness fills (~334 us) and the kernel is already ~95 us.
// A register prefetch ring with static indices (full unroll) forces >=7
// outstanding loads per wave independent of compiler alias analysis:
// 8 waves/SIMD x 8 x 256 B = 16 KiB/SIMD in flight, 6x the Little's-law
// requirement for 6.3 TB/s at ~900 cyc HBM latency.

static constexpr int   T_STEPS = 128;
static constexpr int   N_FEAT  = 8192;   // 2^13
static constexpr int   DEPTH   = 8;      // prefetch distance
static constexpr float TAU     = 0.25f;
static constexpr float V_TH    = 1.0f;

__global__ __launch_bounds__(256) void lif_scan_kernel(
    const float* __restrict__ x, float* __restrict__ out, int n_chains) {
    int tid = blockIdx.x * blockDim.x + threadIdx.x;  // 0 .. B*N-1
    if (tid >= n_chains) return;

    int b = tid >> 13;            // tid / N_FEAT
    int n = tid & (N_FEAT - 1);   // tid % N_FEAT
    // element index of [b, t, n] is (b*T + t)*N + n
    const size_t base = (size_t)b * T_STEPS * N_FEAT + n;

    float buf[DEPTH];
    // Prime the pipeline: DEPTH independent loads issued back-to-back.
#pragma unroll
    for (int d = 0; d < DEPTH; ++d)
        buf[d] = __builtin_nontemporal_load(&x[base + (size_t)d * N_FEAT]);

    float mem = 0.f;
    // Full unroll: t % DEPTH becomes a compile-time constant, so buf[] stays
    // in registers and each consume waits only on its own load.
#pragma unroll
    for (int t = 0; t < T_STEPS; ++t) {
        float xt = buf[t & (DEPTH - 1)];
        if (t + DEPTH < T_STEPS)
            buf[t & (DEPTH - 1)] =
                __builtin_nontemporal_load(&x[base + (size_t)(t + DEPTH) * N_FEAT]);
        // 0.25*mem is exact (pow2 scale) -> bitwise matches numpy reference
        mem = TAU * mem + xt;
        float s = (mem > V_TH) ? 1.f : 0.f;
        mem     = (mem > V_TH) ? 0.f : mem;
        __builtin_nontemporal_store(s, &out[base + (size_t)t * N_FEAT]);
    }
}

extern "C" void kernel_launch(void* const* d_in, const int* in_sizes, int n_in,
                              void* d_out, int out_size, void* d_ws, size_t ws_size,
                              hipStream_t stream) {
    const float* x   = (const float*)d_in[0];
    float*       out = (float*)d_out;

    int total    = in_sizes[0];          // B*T*N
    int n_chains = total / T_STEPS;      // B*N
    int block    = 256;
    int grid     = (n_chains + block - 1) / block;

    lif_scan_kernel<<<grid, block, 0, stream>>>(x, out, n_chains);
}